// Round 6
// baseline (1087.497 us; speedup 1.0000x reference)
//
#include <hip/hip_runtime.h>
#include <hip/hip_cooperative_groups.h>
#include <math.h>

namespace cg = cooperative_groups;

#define N 4096
#define DQ 128
#define DIN 64
#define DC 32
#define NT 9          // full B panel: 9 n-tiles (128 v cols + z tile)
#define PST9 144
#define NIT 256       // N/16 i-tiles
#define KB 4          // k-splits (rounds 1-2)
#define SW 8          // k-steps per wave: N / KB / 32 rows / 4 waves
#define TS 68         // exp wave-tile row stride in f16 units
#define SMEM_ALL 36864

typedef __attribute__((ext_vector_type(8))) short short8;
typedef __attribute__((ext_vector_type(8))) _Float16 half8;
typedef __attribute__((ext_vector_type(4))) float f32x4;
typedef __attribute__((ext_vector_type(4))) unsigned short us4;

__device__ __forceinline__ unsigned short f2h(float x) {
  return __builtin_bit_cast(unsigned short, (_Float16)x);
}
__device__ __forceinline__ half8 ldfrag(const unsigned short* p) {
  return __builtin_bit_cast(half8, *(const short8*)p);
}
__device__ __forceinline__ void gsync() {
  __threadfence();                 // release: publish writes device-wide
  cg::this_grid().sync();
  __threadfence();                 // acquire: invalidate stale lines
}

// u = W_ad_k . wa (float4 row reads)
__device__ __forceinline__ void u_calc(int tid, const float* __restrict__ W_ad_k,
                                       const float* __restrict__ wa, float* u) {
  if (tid < DQ) {
    float s = 0.f;
    const float* wrow = &W_ad_k[tid * DQ];
    for (int q = 0; q < DQ; q += 4) {
      const float4 wv = *(const float4*)&wrow[q];
      const float4 av = *(const float4*)&wa[q];
      s += wv.x * av.x + wv.y * av.y + wv.z * av.z + wv.w * av.w;
    }
    u[tid] = s;
  }
}

// p*(h@W_av+b_av) -> single f16 tile in LDS
__device__ __forceinline__ void v_phase(const float* hs_row, float p,
    const float* __restrict__ W_av_k, const float* __restrict__ b_av_k,
    int r, int d4, unsigned short* shh) {
  float a[4] = {b_av_k[d4], b_av_k[d4 + 1], b_av_k[d4 + 2], b_av_k[d4 + 3]};
  for (int c = 0; c < DQ; ++c) {
    const float hv = hs_row[c];
    const float4 w = *(const float4*)&W_av_k[c * DQ + d4];
    a[0] += hv * w.x; a[1] += hv * w.y; a[2] += hv * w.z; a[3] += hv * w.w;
  }
  const int nt = d4 >> 4;
#pragma unroll
  for (int e = 0; e < 4; ++e)
    shh[nt * 128 + ((d4 + e) & 15) * 8 + r] = f2h(p * a[e]);
  const int c32 = d4 >> 2;
  if (c32 < 16)
    shh[8 * 128 + c32 * 8 + r] = (c32 == 0) ? f2h(p) : 0;
}

__device__ __forceinline__ void v_store(int tid, int blk,
    const unsigned short* shh, unsigned short* __restrict__ Vf) {
  const int kt = blk >> 2, quad = blk & 3;
  if (tid < NT * 16) {
    const int nt = tid >> 4, l15 = tid & 15;
    const size_t dst = (((size_t)kt * NT + nt) * 64 + quad * 16 + l15) * 8;
    *(short8*)(Vf + dst) = *(const short8*)&shh[nt * 128 + l15 * 8];
  }
}

// ---- one 32x256 exp panel: wave-private, barrier-free ----------------------
__device__ __forceinline__ void exp_body(int pid, int tid,
    const float* __restrict__ trans, unsigned short* __restrict__ Ef,
    char* smem) {
  const int ip = pid & 15;          // i-panel of 256
  const int kt = pid >> 4;          // k-tile of 32
  const int w = tid >> 6, lane = tid & 63;
  const int quad = lane >> 4, l15 = lane & 15;
  unsigned short* lt = (unsigned short*)smem + w * (32 * TS);
  float4 v[8];
#pragma unroll
  for (int p = 0; p < 8; ++p) {
    const int r = 4 * p + quad;
    v[p] = *(const float4*)&trans[(size_t)(kt * 32 + r) * N + ip * 256 + w * 64 + 4 * l15];
  }
#pragma unroll
  for (int p = 0; p < 8; ++p) {
    const int r = 4 * p + quad;
    us4 pv;
    pv.x = f2h(__expf(v[p].x)); pv.y = f2h(__expf(v[p].y));
    pv.z = f2h(__expf(v[p].z)); pv.w = f2h(__expf(v[p].w));
    *(us4*)&lt[r * TS + 4 * l15] = pv;
  }
  asm volatile("s_waitcnt lgkmcnt(0)" ::: "memory");  // in-wave write->read fence
#pragma unroll
  for (int s = 0; s < 4; ++s) {
    unsigned short hb[8];
#pragma unroll
    for (int jj = 0; jj < 8; ++jj)
      hb[jj] = lt[(quad * 8 + jj) * TS + s * 16 + l15];
    const short8 sv = {(short)hb[0], (short)hb[1], (short)hb[2], (short)hb[3],
                       (short)hb[4], (short)hb[5], (short)hb[6], (short)hb[7]};
    const int itt = ip * 16 + 4 * w + s;
    *(short8*)(Ef + (((size_t)kt * NIT + itt) * 64 + lane) * 8) = sv;
  }
}

// ---- round 0: encode + sa + p + V' (8 rows per unit) ------------------------
__device__ __forceinline__ void vs0_body(int blk, int tid,
    const float* __restrict__ x, const float* __restrict__ comms,
    const float* __restrict__ W_enc, const float* __restrict__ b_enc,
    const float* __restrict__ W_ad0, const float* __restrict__ wa0,
    const float* __restrict__ W_av0, const float* __restrict__ b_av0,
    unsigned short* __restrict__ Vf, char* smem) {
  float(*xs)[96] = (float(*)[96])smem;                       // 3072 B
  float(*hs)[DQ] = (float(*)[DQ])(smem + 3072);              // 4096 B
  float* u = (float*)(smem + 7168);                          // 512 B
  float* pb = (float*)(smem + 7680);                         // 32 B
  unsigned short* shh = (unsigned short*)(smem + 7712);      // 2304 B
  if (tid < 128) {
    const float4 vv = *(const float4*)&x[(size_t)blk * 8 * DIN + tid * 4];
    const int idx = tid * 4, r = idx >> 6, c = idx & 63;
    xs[r][c] = vv.x; xs[r][c + 1] = vv.y; xs[r][c + 2] = vv.z; xs[r][c + 3] = vv.w;
  } else if (tid < 192) {
    const int t = tid - 128;
    const float4 vv = *(const float4*)&comms[(size_t)blk * 8 * DC + t * 4];
    const int idx = t * 4, r = idx >> 5, c = idx & 31;
    xs[r][64 + c] = vv.x; xs[r][64 + c + 1] = vv.y;
    xs[r][64 + c + 2] = vv.z; xs[r][64 + c + 3] = vv.w;
  }
  u_calc(tid, W_ad0, wa0, u);
  __syncthreads();
  const int r = tid >> 5, c32 = tid & 31, d4 = c32 * 4;
  {
    float a0 = b_enc[d4], a1 = b_enc[d4 + 1], a2 = b_enc[d4 + 2], a3 = b_enc[d4 + 3];
    for (int c = 0; c < 96; ++c) {
      const float hv = xs[r][c];
      const float4 w = *(const float4*)&W_enc[c * DQ + d4];
      a0 += hv * w.x; a1 += hv * w.y; a2 += hv * w.z; a3 += hv * w.w;
    }
    hs[r][d4] = a0; hs[r][d4 + 1] = a1; hs[r][d4 + 2] = a2; hs[r][d4 + 3] = a3;
  }
  __syncthreads();
  float part = 0.f;
  for (int c = c32; c < DQ; c += 32) part += hs[r][c] * u[c];
#pragma unroll
  for (int m = 16; m > 0; m >>= 1) part += __shfl_xor(part, m, 32);
  if (c32 == 0) pb[r] = __expf(part);
  __syncthreads();
  v_phase(hs[r], pb[r], W_av0, b_av0, r, d4, shh);
  __syncthreads();
  v_store(tid, blk, shh, Vf);
}

// ---- rounds 1: P-reduce -> h + sa + p + V' ---------------------------------
__device__ __forceinline__ void vsr_body(int blk, int tid,
    const float* __restrict__ P, const float* __restrict__ W_ad_k,
    const float* __restrict__ wa, const float* __restrict__ W_av_k,
    const float* __restrict__ b_av_k, unsigned short* __restrict__ Vf,
    char* smem) {
  float(*hs)[DQ] = (float(*)[DQ])smem;                       // 4096 B
  float* u = (float*)(smem + 4096);                          // 512 B
  float* pb = (float*)(smem + 4608);                         // 32 B
  unsigned short* shh = (unsigned short*)(smem + 4640);      // 2304 B
  const int r = tid >> 5, c32 = tid & 31, d4 = c32 * 4;
  const int j = blk * 8 + r;
  u_calc(tid, W_ad_k, wa, u);
  float4 num = {0.f, 0.f, 0.f, 0.f};
  float den = 0.f;
#pragma unroll
  for (int s = 0; s < KB; ++s) {
    const float* b = &P[((size_t)s * N + j) * PST9];
    const float4 v = *(const float4*)&b[d4];
    num.x += v.x; num.y += v.y; num.z += v.z; num.w += v.w;
    den += b[128];
  }
  const float inv = 1.f / den;
  hs[r][d4] = num.x * inv; hs[r][d4 + 1] = num.y * inv;
  hs[r][d4 + 2] = num.z * inv; hs[r][d4 + 3] = num.w * inv;
  __syncthreads();
  float part = 0.f;
  for (int c = c32; c < DQ; c += 32) part += hs[r][c] * u[c];
#pragma unroll
  for (int m = 16; m > 0; m >>= 1) part += __shfl_xor(part, m, 32);
  if (c32 == 0) pb[r] = __expf(part);
  __syncthreads();
  v_phase(hs[r], pb[r], W_av_k, b_av_k, r, d4, shh);
  __syncthreads();
  v_store(tid, blk, shh, Vf);
}

// ---- round 2: P-reduce -> h + sa + p + CONTRACTED V' ------------------------
__device__ __forceinline__ void vsrc_body(int blk, int tid,
    const float* __restrict__ P, const float* __restrict__ W_ad_k,
    const float* __restrict__ wa, const float* __restrict__ W_av_k,
    const float* __restrict__ b_av_k, const float* __restrict__ W_dec,
    unsigned short* __restrict__ Vc, char* smem) {
  float(*hs)[DQ] = (float(*)[DQ])smem;
  float* u = (float*)(smem + 4096);
  float* pb = (float*)(smem + 4608);
  const int r = tid >> 5, c32 = tid & 31, d4 = c32 * 4;
  const int j = blk * 8 + r;
  u_calc(tid, W_ad_k, wa, u);
  float4 num = {0.f, 0.f, 0.f, 0.f};
  float den = 0.f;
#pragma unroll
  for (int s = 0; s < KB; ++s) {
    const float* b = &P[((size_t)s * N + j) * PST9];
    const float4 v = *(const float4*)&b[d4];
    num.x += v.x; num.y += v.y; num.z += v.z; num.w += v.w;
    den += b[128];
  }
  const float inv = 1.f / den;
  hs[r][d4] = num.x * inv; hs[r][d4 + 1] = num.y * inv;
  hs[r][d4 + 2] = num.z * inv; hs[r][d4 + 3] = num.w * inv;
  __syncthreads();
  float part = 0.f;
  for (int c = c32; c < DQ; c += 32) part += hs[r][c] * u[c];
#pragma unroll
  for (int m = 16; m > 0; m >>= 1) part += __shfl_xor(part, m, 32);
  if (c32 == 0) pb[r] = __expf(part);
  __syncthreads();
  float a[4] = {b_av_k[d4], b_av_k[d4 + 1], b_av_k[d4 + 2], b_av_k[d4 + 3]};
  for (int c = 0; c < DQ; ++c) {
    const float hv = hs[r][c];
    const float4 w = *(const float4*)&W_av_k[c * DQ + d4];
    a[0] += hv * w.x; a[1] += hv * w.y; a[2] += hv * w.z; a[3] += hv * w.w;
  }
  float vd = a[0] * W_dec[d4] + a[1] * W_dec[d4 + 1]
           + a[2] * W_dec[d4 + 2] + a[3] * W_dec[d4 + 3];
#pragma unroll
  for (int m = 16; m > 0; m >>= 1) vd += __shfl_xor(vd, m, 32);
  const float p = pb[r];
  if (c32 < 16) {
    const size_t ix = (((size_t)(blk >> 2)) * 64 + (blk & 3) * 16 + c32) * 8 + r;
    Vc[ix] = (c32 == 0) ? f2h(p * vd) : (c32 == 1) ? f2h(p) : 0;
  }
}

// ---- MFMA GEMM, B direct-to-VGPR dbuf; 36 KB two-pass epilogue --------------
__device__ __forceinline__ void gemm_body(int b, int tid,
    const unsigned short* __restrict__ Ef, const unsigned short* __restrict__ Vf,
    float* __restrict__ P, char* smem) {
  float* lf = (float*)smem;
  const int w = tid >> 6, lane = tid & 63;
  const int quad = lane >> 4, l15 = lane & 15;
  const int it0 = (b & 127) * 2;
  const int y = b >> 7;
  const size_t ktw = (size_t)y * (4 * SW) + w * SW;

  f32x4 acc[2][NT];
#pragma unroll
  for (int ti = 0; ti < 2; ++ti)
#pragma unroll
    for (int nt = 0; nt < NT; ++nt) acc[ti][nt] = (f32x4){0.f, 0.f, 0.f, 0.f};

  const unsigned short* Ap = Ef + (ktw * NIT + it0) * 512 + lane * 8;
  const unsigned short* Bp = Vf + ktw * (NT * 512) + lane * 8;

  half8 A0[2], A1[2], B0[NT], B1[NT];
#pragma unroll
  for (int ti = 0; ti < 2; ++ti) A0[ti] = ldfrag(Ap + ti * 512);
#pragma unroll
  for (int nt = 0; nt < NT; ++nt) B0[nt] = ldfrag(Bp + nt * 512);

#pragma unroll
  for (int t = 0; t < SW; ++t) {
    if (t + 1 < SW) {
      const unsigned short* An = Ap + (size_t)(t + 1) * (NIT * 512);
      const unsigned short* Bn = Bp + (size_t)(t + 1) * (NT * 512);
#pragma unroll
      for (int nt = 0; nt < NT; ++nt) B1[nt] = ldfrag(Bn + nt * 512);
#pragma unroll
      for (int ti = 0; ti < 2; ++ti) A1[ti] = ldfrag(An + ti * 512);
    }
#pragma unroll
    for (int nt = 0; nt < NT; ++nt) {
      acc[0][nt] = __builtin_amdgcn_mfma_f32_16x16x32_f16(A0[0], B0[nt], acc[0][nt], 0, 0, 0);
      acc[1][nt] = __builtin_amdgcn_mfma_f32_16x16x32_f16(A0[1], B0[nt], acc[1][nt], 0, 0, 0);
    }
    if (t + 1 < SW) {
      A0[0] = A1[0]; A0[1] = A1[1];
#pragma unroll
      for (int nt = 0; nt < NT; ++nt) B0[nt] = B1[nt];
    }
  }
  float* Pb = P + (size_t)y * N * PST9;
#pragma unroll
  for (int ti = 0; ti < 2; ++ti) {
    __syncthreads();
#pragma unroll
    for (int nt = 0; nt < NT; ++nt) {
      float4 v; v.x = acc[ti][nt][0]; v.y = acc[ti][nt][1];
      v.z = acc[ti][nt][2]; v.w = acc[ti][nt][3];
      *(float4*)&lf[(w * NT + nt) * 256 + lane * 4] = v;
    }
    __syncthreads();
    for (int p = w; p < NT; p += 4) {
      float4 s = {0.f, 0.f, 0.f, 0.f};
#pragma unroll
      for (int wv = 0; wv < 4; ++wv) {
        const float4 v = *(const float4*)&lf[(wv * NT + p) * 256 + lane * 4];
        s.x += v.x; s.y += v.y; s.z += v.z; s.w += v.w;
      }
      const float sr[4] = {s.x, s.y, s.z, s.w};
      if (p != 8 || l15 == 0) {
#pragma unroll
        for (int r2 = 0; r2 < 4; ++r2) {
          const int i = (it0 + ti) * 16 + quad * 4 + r2;
          Pb[(size_t)i * PST9 + p * 16 + l15] = sr[r2];
        }
      }
    }
  }
}

// ---- round-3 GEMM partials: block b = (it, k-half); num/den -> P3 ----------
__device__ __forceinline__ void gemmo_body(int b, int tid,
    const unsigned short* __restrict__ Ef, const unsigned short* __restrict__ Vc,
    float* __restrict__ P3, char* smem) {
  float* red = (float*)smem;           // 4 KB
  const int w = tid >> 6, lane = tid & 63;
  const int it = b >> 1, kh = b & 1;
  const int kt0 = kh * 64 + w * 16;
  half8 Af[16], Bf[16];
#pragma unroll
  for (int t = 0; t < 16; ++t) {
    const size_t kt = kt0 + t;
    Af[t] = ldfrag(Ef + ((kt * NIT + it) * 64 + lane) * 8);
    Bf[t] = ldfrag(Vc + (kt * 64 + lane) * 8);
  }
  f32x4 acc = (f32x4){0.f, 0.f, 0.f, 0.f};
#pragma unroll
  for (int t = 0; t < 16; ++t)
    acc = __builtin_amdgcn_mfma_f32_16x16x32_f16(Af[t], Bf[t], acc, 0, 0, 0);
  float4 v; v.x = acc[0]; v.y = acc[1]; v.z = acc[2]; v.w = acc[3];
  *(float4*)&red[w * 256 + lane * 4] = v;
  __syncthreads();
  const int l = tid & 63, e = tid >> 6;
  float s = 0.f;
#pragma unroll
  for (int ww = 0; ww < 4; ++ww) s += red[ww * 256 + l * 4 + e];
  const int col = l & 15, row = (l >> 4) * 4 + e;  // C-frag mapping
  if (col == 0) P3[b * 32 + row] = s;
  else if (col == 1) P3[b * 32 + 16 + row] = s;
}

// ---- cooperative mega-kernel: all phases, zero dispatch boundaries ----------
__global__ __launch_bounds__(256, 2) void kAll(
    const float* __restrict__ trans, const float* __restrict__ x,
    const float* __restrict__ comms, const int* __restrict__ mask,
    const float* __restrict__ W_enc, const float* __restrict__ b_enc,
    const float* __restrict__ W_ad, const float* __restrict__ w_att,
    const float* __restrict__ W_av, const float* __restrict__ b_av,
    const float* __restrict__ W_dec, const float* __restrict__ b_dec,
    float* __restrict__ out, unsigned short* __restrict__ Ef,
    unsigned short* __restrict__ Vf, unsigned short* __restrict__ Vc,
    float* __restrict__ P, float* __restrict__ P3) {
  __shared__ __align__(16) char smem[SMEM_ALL];
  const int b = blockIdx.x, tid = threadIdx.x;
  // phase 0: 4 exp panels + 1 VS0 unit per block
#pragma unroll 1
  for (int pp = 0; pp < 4; ++pp) exp_body(b * 4 + pp, tid, trans, Ef, smem);
  __syncthreads();
  vs0_body(b, tid, x, comms, W_enc, b_enc, W_ad, w_att, W_av, b_av, Vf, smem);
  gsync();
  gemm_body(b, tid, Ef, Vf, P, smem);               // round 1 GEMM
  gsync();
  vsr_body(b, tid, P, W_ad + DQ * DQ, w_att + 2 * DQ,
           W_av + (size_t)DQ * DQ, b_av + DQ, Vf, smem);
  gsync();
  gemm_body(b, tid, Ef, Vf, P, smem);               // round 2 GEMM
  gsync();
  vsrc_body(b, tid, P, W_ad + (size_t)2 * DQ * DQ, w_att + 4 * DQ,
            W_av + (size_t)2 * DQ * DQ, b_av + 2 * DQ, W_dec, Vc, smem);
  gsync();
  gemmo_body(b, tid, Ef, Vc, P3, smem);             // round 3 partials
  gsync();
  if (b < 16) {                                     // final out
    const int i = b * 256 + tid;
    const int it = i >> 4, row = i & 15;
    const float num = P3[it * 64 + row] + P3[it * 64 + 32 + row];
    const float den = P3[it * 64 + 16 + row] + P3[it * 64 + 48 + row];
    out[i] = (mask[i] == 0) ? -INFINITY : num / den + b_dec[0];
  }
}

// ================= fallback: verified round-4 six-dispatch path ==============
__global__ __launch_bounds__(256) void kPre(
    const float* __restrict__ trans, unsigned short* __restrict__ Ef,
    const float* __restrict__ x, const float* __restrict__ comms,
    const float* __restrict__ W_enc, const float* __restrict__ b_enc,
    const float* __restrict__ W_ad_k, const float* __restrict__ wa,
    const float* __restrict__ W_av_k, const float* __restrict__ b_av_k,
    unsigned short* __restrict__ Vf) {
  __shared__ __align__(16) char smem[4 * 32 * TS * 2];
  if (blockIdx.x >= 512)
    exp_body(blockIdx.x - 512, threadIdx.x, trans, Ef, smem);
  else
    vs0_body(blockIdx.x, threadIdx.x, x, comms, W_enc, b_enc, W_ad_k, wa,
             W_av_k, b_av_k, Vf, smem);
}

__global__ __launch_bounds__(256) void kVSR(const float* __restrict__ P,
    const float* __restrict__ W_ad_k, const float* __restrict__ wa,
    const float* __restrict__ W_av_k, const float* __restrict__ b_av_k,
    unsigned short* __restrict__ Vf) {
  __shared__ __align__(16) char smem[7168];
  vsr_body(blockIdx.x, threadIdx.x, P, W_ad_k, wa, W_av_k, b_av_k, Vf, smem);
}

__global__ __launch_bounds__(256) void kVSRc(const float* __restrict__ P,
    const float* __restrict__ W_ad_k, const float* __restrict__ wa,
    const float* __restrict__ W_av_k, const float* __restrict__ b_av_k,
    const float* __restrict__ W_dec, unsigned short* __restrict__ Vc) {
  __shared__ __align__(16) char smem[7168];
  vsrc_body(blockIdx.x, threadIdx.x, P, W_ad_k, wa, W_av_k, b_av_k, W_dec, Vc, smem);
}

__global__ __launch_bounds__(256, 2) void kGemmR9(
    const unsigned short* __restrict__ Ef, const unsigned short* __restrict__ Vf,
    float* __restrict__ P) {
  __shared__ __align__(16) char smem[SMEM_ALL];
  gemm_body(blockIdx.y * 128 + blockIdx.x, threadIdx.x, Ef, Vf, P, smem);
}

__global__ __launch_bounds__(512, 2) void kGemmO(
    const unsigned short* __restrict__ Ef, const unsigned short* __restrict__ Vc,
    const float* __restrict__ b_dec, const int* __restrict__ mask,
    float* __restrict__ out) {
  __shared__ float red[8 * 256];
  __shared__ float nums[16], dens[16];
  const int tid = threadIdx.x;
  const int w = tid >> 6, lane = tid & 63;
  const int it = blockIdx.x;
  const int kt0 = w * 16;
  half8 Af[16], Bf[16];
#pragma unroll
  for (int t = 0; t < 16; ++t) {
    const size_t kt = kt0 + t;
    Af[t] = ldfrag(Ef + ((kt * NIT + it) * 64 + lane) * 8);
    Bf[t] = ldfrag(Vc + (kt * 64 + lane) * 8);
  }
  f32x4 acc = (f32x4){0.f, 0.f, 0.f, 0.f};
#pragma unroll
  for (int t = 0; t < 16; ++t)
    acc = __builtin_amdgcn_mfma_f32_16x16x32_f16(Af[t], Bf[t], acc, 0, 0, 0);
  float4 v; v.x = acc[0]; v.y = acc[1]; v.z = acc[2]; v.w = acc[3];
  *(float4*)&red[w * 256 + lane * 4] = v;
  __syncthreads();
  if (tid < 256) {
    const int l = tid & 63, e = tid >> 6;
    float s = 0.f;
#pragma unroll
    for (int ww = 0; ww < 8; ++ww) s += red[ww * 256 + l * 4 + e];
    const int col = l & 15, row = (l >> 4) * 4 + e;
    if (col == 0) nums[row] = s;
    else if (col == 1) dens[row] = s;
  }
  __syncthreads();
  if (tid < 16) {
    const int i = it * 16 + tid;
    out[i] = (mask[i] == 0) ? -INFINITY : nums[tid] / dens[tid] + b_dec[0];
  }
}

extern "C" void kernel_launch(void* const* d_in, const int* in_sizes, int n_in,
                              void* d_out, int out_size, void* d_ws, size_t ws_size,
                              hipStream_t stream) {
  (void)in_sizes; (void)n_in; (void)out_size; (void)ws_size;
  const float* trans = (const float*)d_in[2];
  const float* x     = (const float*)d_in[0];
  const float* comms = (const float*)d_in[1];
  const int*   mask  = (const int*)d_in[3];
  const float* W_enc = (const float*)d_in[4];
  const float* b_enc = (const float*)d_in[5];
  const float* W_ad  = (const float*)d_in[6];
  // d_in[7]=b_ad, d_in[9]=b_att cancel inside the row softmax
  const float* w_att = (const float*)d_in[8];
  const float* W_av  = (const float*)d_in[10];
  const float* b_av  = (const float*)d_in[11];
  const float* W_dec = (const float*)d_in[12];
  const float* b_dec = (const float*)d_in[13];
  float* out         = (float*)d_out;

  char* ws = (char*)d_ws;
  unsigned short* Vf = (unsigned short*)ws;  ws += (size_t)(N / 32) * NT * 512 * 2;
  unsigned short* Vc = (unsigned short*)ws;  ws += (size_t)(N / 32) * 512 * 2;
  unsigned short* Ef = (unsigned short*)ws;  ws += (size_t)N * N * 2;
  float* P  = (float*)ws;                    ws += (size_t)KB * N * PST9 * 4;
  float* P3 = (float*)ws;

  void* args[] = {(void*)&trans, (void*)&x, (void*)&comms, (void*)&mask,
                  (void*)&W_enc, (void*)&b_enc, (void*)&W_ad, (void*)&w_att,
                  (void*)&W_av, (void*)&b_av, (void*)&W_dec, (void*)&b_dec,
                  (void*)&out, (void*)&Ef, (void*)&Vf, (void*)&Vc,
                  (void*)&P, (void*)&P3};
  if (hipLaunchCooperativeKernel(kAll, dim3(512), dim3(256), args, 0, stream)
      == hipSuccess)
    return;

  // fallback: verified 6-dispatch path (round 4, 211 us)
  kPre<<<2560, 256, 0, stream>>>(trans, Ef, x, comms, W_enc, b_enc, W_ad,
                                 w_att, W_av, b_av, Vf);
  kGemmR9<<<dim3(128, KB), 256, 0, stream>>>(Ef, Vf, P);
  kVSR<<<N / 8, 256, 0, stream>>>(P, W_ad + (size_t)DQ * DQ,
                                  w_att + 2 * DQ, W_av + (size_t)DQ * DQ,
                                  b_av + DQ, Vf);
  kGemmR9<<<dim3(128, KB), 256, 0, stream>>>(Ef, Vf, P);
  kVSRc<<<N / 8, 256, 0, stream>>>(P, W_ad + (size_t)2 * DQ * DQ,
                                   w_att + 4 * DQ, W_av + (size_t)2 * DQ * DQ,
                                   b_av + 2 * DQ, W_dec, Vc);
  kGemmO<<<NIT, 512, 0, stream>>>(Ef, Vc, b_dec, mask, out);
}

// Round 10
// 872.112 us; speedup vs baseline: 1.2470x; 1.2470x over previous
//
#include <hip/hip_runtime.h>
#include <math.h>

#define N 4096
#define DQ 128
#define DIN 64
#define DC 32
#define NT 9          // full B panel: 9 n-tiles (128 v cols + z tile)
#define PST9 144
#define NIT 256       // N/16 i-tiles
#define KB 4          // k-splits (rounds 1-2)
#define SW 8          // k-steps per wave: N / KB / 32 rows / 4 waves
#define TS 68         // exp wave-tile row stride in f16 units
#define SMEM_ALL 36864
#define NBLK 512u

typedef __attribute__((ext_vector_type(8))) short short8;
typedef __attribute__((ext_vector_type(8))) _Float16 half8;
typedef __attribute__((ext_vector_type(4))) float f32x4;
typedef __attribute__((ext_vector_type(4))) unsigned short us4;

__device__ __forceinline__ unsigned short f2h(float x) {
  return __builtin_bit_cast(unsigned short, (_Float16)x);
}
__device__ __forceinline__ half8 ldfrag(const unsigned short* p) {
  return __builtin_bit_cast(half8, *(const short8*)p);
}

// ---- lean grid barrier: ping-pong arrive counters + generation counter ------
// bar[0]/bar[16]: arrive counters (parity g&1); bar[32]: generation.
// cnt[g&1] reused only at gen g+2; its reset is release-ordered before the
// gen bump, so acquirers of gen >= g+1 always see the reset. ~us-scale vs
// cg::this_grid().sync()'s ~120us (measured r6: (990-160)/7).
__device__ __forceinline__ void gbar(unsigned* bar, int tid) {
  __syncthreads();
  __threadfence();                 // release: publish phase writes device-wide
  if (tid == 0) {
    const unsigned g = __hip_atomic_load(&bar[32], __ATOMIC_RELAXED,
                                         __HIP_MEMORY_SCOPE_AGENT);
    unsigned* cnt = &bar[(g & 1) * 16];
    const unsigned a = __hip_atomic_fetch_add(cnt, 1u, __ATOMIC_ACQ_REL,
                                              __HIP_MEMORY_SCOPE_AGENT);
    if (a == NBLK - 1) {
      __hip_atomic_store(cnt, 0u, __ATOMIC_RELAXED, __HIP_MEMORY_SCOPE_AGENT);
      __hip_atomic_fetch_add(&bar[32], 1u, __ATOMIC_RELEASE,
                             __HIP_MEMORY_SCOPE_AGENT);
    } else {
      while (__hip_atomic_load(&bar[32], __ATOMIC_ACQUIRE,
                               __HIP_MEMORY_SCOPE_AGENT) == g)
        __builtin_amdgcn_s_sleep(8);
    }
  }
  __syncthreads();
  __threadfence();                 // acquire: invalidate stale lines
}

// u = W_ad_k . wa (float4 row reads)
__device__ __forceinline__ void u_calc(int tid, const float* __restrict__ W_ad_k,
                                       const float* __restrict__ wa, float* u) {
  if (tid < DQ) {
    float s = 0.f;
    const float* wrow = &W_ad_k[tid * DQ];
    for (int q = 0; q < DQ; q += 4) {
      const float4 wv = *(const float4*)&wrow[q];
      const float4 av = *(const float4*)&wa[q];
      s += wv.x * av.x + wv.y * av.y + wv.z * av.z + wv.w * av.w;
    }
    u[tid] = s;
  }
}

// p*(h@W_av+b_av) -> single f16 tile in LDS
__device__ __forceinline__ void v_phase(const float* hs_row, float p,
    const float* __restrict__ W_av_k, const float* __restrict__ b_av_k,
    int r, int d4, unsigned short* shh) {
  float a[4] = {b_av_k[d4], b_av_k[d4 + 1], b_av_k[d4 + 2], b_av_k[d4 + 3]};
  for (int c = 0; c < DQ; ++c) {
    const float hv = hs_row[c];
    const float4 w = *(const float4*)&W_av_k[c * DQ + d4];
    a[0] += hv * w.x; a[1] += hv * w.y; a[2] += hv * w.z; a[3] += hv * w.w;
  }
  const int nt = d4 >> 4;
#pragma unroll
  for (int e = 0; e < 4; ++e)
    shh[nt * 128 + ((d4 + e) & 15) * 8 + r] = f2h(p * a[e]);
  const int c32 = d4 >> 2;
  if (c32 < 16)
    shh[8 * 128 + c32 * 8 + r] = (c32 == 0) ? f2h(p) : 0;
}

__device__ __forceinline__ void v_store(int tid, int blk,
    const unsigned short* shh, unsigned short* __restrict__ Vf) {
  const int kt = blk >> 2, quad = blk & 3;
  if (tid < NT * 16) {
    const int nt = tid >> 4, l15 = tid & 15;
    const size_t dst = (((size_t)kt * NT + nt) * 64 + quad * 16 + l15) * 8;
    *(short8*)(Vf + dst) = *(const short8*)&shh[nt * 128 + l15 * 8];
  }
}

// ---- one 32x256 exp panel: wave-private, barrier-free ----------------------
__device__ __forceinline__ void exp_body(int pid, int tid,
    const float* __restrict__ trans, unsigned short* __restrict__ Ef,
    char* smem) {
  const int ip = pid & 15;          // i-panel of 256
  const int kt = pid >> 4;          // k-tile of 32
  const int w = tid >> 6, lane = tid & 63;
  const int quad = lane >> 4, l15 = lane & 15;
  unsigned short* lt = (unsigned short*)smem + w * (32 * TS);
  float4 v[8];
#pragma unroll
  for (int p = 0; p < 8; ++p) {
    const int r = 4 * p + quad;
    v[p] = *(const float4*)&trans[(size_t)(kt * 32 + r) * N + ip * 256 + w * 64 + 4 * l15];
  }
#pragma unroll
  for (int p = 0; p < 8; ++p) {
    const int r = 4 * p + quad;
    us4 pv;
    pv.x = f2h(__expf(v[p].x)); pv.y = f2h(__expf(v[p].y));
    pv.z = f2h(__expf(v[p].z)); pv.w = f2h(__expf(v[p].w));
    *(us4*)&lt[r * TS + 4 * l15] = pv;
  }
  asm volatile("s_waitcnt lgkmcnt(0)" ::: "memory");  // in-wave write->read fence
#pragma unroll
  for (int s = 0; s < 4; ++s) {
    unsigned short hb[8];
#pragma unroll
    for (int jj = 0; jj < 8; ++jj)
      hb[jj] = lt[(quad * 8 + jj) * TS + s * 16 + l15];
    const short8 sv = {(short)hb[0], (short)hb[1], (short)hb[2], (short)hb[3],
                       (short)hb[4], (short)hb[5], (short)hb[6], (short)hb[7]};
    const int itt = ip * 16 + 4 * w + s;
    *(short8*)(Ef + (((size_t)kt * NIT + itt) * 64 + lane) * 8) = sv;
  }
}

// ---- round 0: encode + sa + p + V' (8 rows per unit) ------------------------
__device__ __forceinline__ void vs0_body(int blk, int tid,
    const float* __restrict__ x, const float* __restrict__ comms,
    const float* __restrict__ W_enc, const float* __restrict__ b_enc,
    const float* __restrict__ W_ad0, const float* __restrict__ wa0,
    const float* __restrict__ W_av0, const float* __restrict__ b_av0,
    unsigned short* __restrict__ Vf, char* smem) {
  float(*xs)[96] = (float(*)[96])smem;                       // 3072 B
  float(*hs)[DQ] = (float(*)[DQ])(smem + 3072);              // 4096 B
  float* u = (float*)(smem + 7168);                          // 512 B
  float* pb = (float*)(smem + 7680);                         // 32 B
  unsigned short* shh = (unsigned short*)(smem + 7712);      // 2304 B
  if (tid < 128) {
    const float4 vv = *(const float4*)&x[(size_t)blk * 8 * DIN + tid * 4];
    const int idx = tid * 4, r = idx >> 6, c = idx & 63;
    xs[r][c] = vv.x; xs[r][c + 1] = vv.y; xs[r][c + 2] = vv.z; xs[r][c + 3] = vv.w;
  } else if (tid < 192) {
    const int t = tid - 128;
    const float4 vv = *(const float4*)&comms[(size_t)blk * 8 * DC + t * 4];
    const int idx = t * 4, r = idx >> 5, c = idx & 31;
    xs[r][64 + c] = vv.x; xs[r][64 + c + 1] = vv.y;
    xs[r][64 + c + 2] = vv.z; xs[r][64 + c + 3] = vv.w;
  }
  u_calc(tid, W_ad0, wa0, u);
  __syncthreads();
  const int r = tid >> 5, c32 = tid & 31, d4 = c32 * 4;
  {
    float a0 = b_enc[d4], a1 = b_enc[d4 + 1], a2 = b_enc[d4 + 2], a3 = b_enc[d4 + 3];
    for (int c = 0; c < 96; ++c) {
      const float hv = xs[r][c];
      const float4 w = *(const float4*)&W_enc[c * DQ + d4];
      a0 += hv * w.x; a1 += hv * w.y; a2 += hv * w.z; a3 += hv * w.w;
    }
    hs[r][d4] = a0; hs[r][d4 + 1] = a1; hs[r][d4 + 2] = a2; hs[r][d4 + 3] = a3;
  }
  __syncthreads();
  float part = 0.f;
  for (int c = c32; c < DQ; c += 32) part += hs[r][c] * u[c];
#pragma unroll
  for (int m = 16; m > 0; m >>= 1) part += __shfl_xor(part, m, 32);
  if (c32 == 0) pb[r] = __expf(part);
  __syncthreads();
  v_phase(hs[r], pb[r], W_av0, b_av0, r, d4, shh);
  __syncthreads();
  v_store(tid, blk, shh, Vf);
}

// ---- rounds 1: P-reduce -> h + sa + p + V' ---------------------------------
__device__ __forceinline__ void vsr_body(int blk, int tid,
    const float* __restrict__ P, const float* __restrict__ W_ad_k,
    const float* __restrict__ wa, const float* __restrict__ W_av_k,
    const float* __restrict__ b_av_k, unsigned short* __restrict__ Vf,
    char* smem) {
  float(*hs)[DQ] = (float(*)[DQ])smem;                       // 4096 B
  float* u = (float*)(smem + 4096);                          // 512 B
  float* pb = (float*)(smem + 4608);                         // 32 B
  unsigned short* shh = (unsigned short*)(smem + 4640);      // 2304 B
  const int r = tid >> 5, c32 = tid & 31, d4 = c32 * 4;
  const int j = blk * 8 + r;
  u_calc(tid, W_ad_k, wa, u);
  float4 num = {0.f, 0.f, 0.f, 0.f};
  float den = 0.f;
#pragma unroll
  for (int s = 0; s < KB; ++s) {
    const float* b = &P[((size_t)s * N + j) * PST9];
    const float4 v = *(const float4*)&b[d4];
    num.x += v.x; num.y += v.y; num.z += v.z; num.w += v.w;
    den += b[128];
  }
  const float inv = 1.f / den;
  hs[r][d4] = num.x * inv; hs[r][d4 + 1] = num.y * inv;
  hs[r][d4 + 2] = num.z * inv; hs[r][d4 + 3] = num.w * inv;
  __syncthreads();
  float part = 0.f;
  for (int c = c32; c < DQ; c += 32) part += hs[r][c] * u[c];
#pragma unroll
  for (int m = 16; m > 0; m >>= 1) part += __shfl_xor(part, m, 32);
  if (c32 == 0) pb[r] = __expf(part);
  __syncthreads();
  v_phase(hs[r], pb[r], W_av_k, b_av_k, r, d4, shh);
  __syncthreads();
  v_store(tid, blk, shh, Vf);
}

// ---- round 2: P-reduce -> h + sa + p + CONTRACTED V' ------------------------
__device__ __forceinline__ void vsrc_body(int blk, int tid,
    const float* __restrict__ P, const float* __restrict__ W_ad_k,
    const float* __restrict__ wa, const float* __restrict__ W_av_k,
    const float* __restrict__ b_av_k, const float* __restrict__ W_dec,
    unsigned short* __restrict__ Vc, char* smem) {
  float(*hs)[DQ] = (float(*)[DQ])smem;
  float* u = (float*)(smem + 4096);
  float* pb = (float*)(smem + 4608);
  const int r = tid >> 5, c32 = tid & 31, d4 = c32 * 4;
  const int j = blk * 8 + r;
  u_calc(tid, W_ad_k, wa, u);
  float4 num = {0.f, 0.f, 0.f, 0.f};
  float den = 0.f;
#pragma unroll
  for (int s = 0; s < KB; ++s) {
    const float* b = &P[((size_t)s * N + j) * PST9];
    const float4 v = *(const float4*)&b[d4];
    num.x += v.x; num.y += v.y; num.z += v.z; num.w += v.w;
    den += b[128];
  }
  const float inv = 1.f / den;
  hs[r][d4] = num.x * inv; hs[r][d4 + 1] = num.y * inv;
  hs[r][d4 + 2] = num.z * inv; hs[r][d4 + 3] = num.w * inv;
  __syncthreads();
  float part = 0.f;
  for (int c = c32; c < DQ; c += 32) part += hs[r][c] * u[c];
#pragma unroll
  for (int m = 16; m > 0; m >>= 1) part += __shfl_xor(part, m, 32);
  if (c32 == 0) pb[r] = __expf(part);
  __syncthreads();
  float a[4] = {b_av_k[d4], b_av_k[d4 + 1], b_av_k[d4 + 2], b_av_k[d4 + 3]};
  for (int c = 0; c < DQ; ++c) {
    const float hv = hs[r][c];
    const float4 w = *(const float4*)&W_av_k[c * DQ + d4];
    a[0] += hv * w.x; a[1] += hv * w.y; a[2] += hv * w.z; a[3] += hv * w.w;
  }
  float vd = a[0] * W_dec[d4] + a[1] * W_dec[d4 + 1]
           + a[2] * W_dec[d4 + 2] + a[3] * W_dec[d4 + 3];
#pragma unroll
  for (int m = 16; m > 0; m >>= 1) vd += __shfl_xor(vd, m, 32);
  const float p = pb[r];
  if (c32 < 16) {
    const size_t ix = (((size_t)(blk >> 2)) * 64 + (blk & 3) * 16 + c32) * 8 + r;
    Vc[ix] = (c32 == 0) ? f2h(p * vd) : (c32 == 1) ? f2h(p) : 0;
  }
}

// ---- MFMA GEMM, B direct-to-VGPR dbuf; 36 KB two-pass epilogue --------------
__device__ __forceinline__ void gemm_body(int b, int tid,
    const unsigned short* __restrict__ Ef, const unsigned short* __restrict__ Vf,
    float* __restrict__ P, char* smem) {
  float* lf = (float*)smem;
  const int w = tid >> 6, lane = tid & 63;
  const int quad = lane >> 4, l15 = lane & 15;
  const int it0 = (b & 127) * 2;
  const int y = b >> 7;
  const size_t ktw = (size_t)y * (4 * SW) + w * SW;

  f32x4 acc[2][NT];
#pragma unroll
  for (int ti = 0; ti < 2; ++ti)
#pragma unroll
    for (int nt = 0; nt < NT; ++nt) acc[ti][nt] = (f32x4){0.f, 0.f, 0.f, 0.f};

  const unsigned short* Ap = Ef + (ktw * NIT + it0) * 512 + lane * 8;
  const unsigned short* Bp = Vf + ktw * (NT * 512) + lane * 8;

  half8 A0[2], A1[2], B0[NT], B1[NT];
#pragma unroll
  for (int ti = 0; ti < 2; ++ti) A0[ti] = ldfrag(Ap + ti * 512);
#pragma unroll
  for (int nt = 0; nt < NT; ++nt) B0[nt] = ldfrag(Bp + nt * 512);

#pragma unroll
  for (int t = 0; t < SW; ++t) {
    if (t + 1 < SW) {
      const unsigned short* An = Ap + (size_t)(t + 1) * (NIT * 512);
      const unsigned short* Bn = Bp + (size_t)(t + 1) * (NT * 512);
#pragma unroll
      for (int nt = 0; nt < NT; ++nt) B1[nt] = ldfrag(Bn + nt * 512);
#pragma unroll
      for (int ti = 0; ti < 2; ++ti) A1[ti] = ldfrag(An + ti * 512);
    }
#pragma unroll
    for (int nt = 0; nt < NT; ++nt) {
      acc[0][nt] = __builtin_amdgcn_mfma_f32_16x16x32_f16(A0[0], B0[nt], acc[0][nt], 0, 0, 0);
      acc[1][nt] = __builtin_amdgcn_mfma_f32_16x16x32_f16(A0[1], B0[nt], acc[1][nt], 0, 0, 0);
    }
    if (t + 1 < SW) {
      A0[0] = A1[0]; A0[1] = A1[1];
#pragma unroll
      for (int nt = 0; nt < NT; ++nt) B0[nt] = B1[nt];
    }
  }
  float* Pb = P + (size_t)y * N * PST9;
#pragma unroll
  for (int ti = 0; ti < 2; ++ti) {
    __syncthreads();
#pragma unroll
    for (int nt = 0; nt < NT; ++nt) {
      float4 v; v.x = acc[ti][nt][0]; v.y = acc[ti][nt][1];
      v.z = acc[ti][nt][2]; v.w = acc[ti][nt][3];
      *(float4*)&lf[(w * NT + nt) * 256 + lane * 4] = v;
    }
    __syncthreads();
    for (int p = w; p < NT; p += 4) {
      float4 s = {0.f, 0.f, 0.f, 0.f};
#pragma unroll
      for (int wv = 0; wv < 4; ++wv) {
        const float4 v = *(const float4*)&lf[(wv * NT + p) * 256 + lane * 4];
        s.x += v.x; s.y += v.y; s.z += v.z; s.w += v.w;
      }
      const float sr[4] = {s.x, s.y, s.z, s.w};
      if (p != 8 || l15 == 0) {
#pragma unroll
        for (int r2 = 0; r2 < 4; ++r2) {
          const int i = (it0 + ti) * 16 + quad * 4 + r2;
          Pb[(size_t)i * PST9 + p * 16 + l15] = sr[r2];
        }
      }
    }
  }
}

// ---- round-3 GEMM partials: block b = (it, k-half); num/den -> P3 ----------
__device__ __forceinline__ void gemmo_body(int b, int tid,
    const unsigned short* __restrict__ Ef, const unsigned short* __restrict__ Vc,
    float* __restrict__ P3, char* smem) {
  float* red = (float*)smem;           // 4 KB
  const int w = tid >> 6, lane = tid & 63;
  const int it = b >> 1, kh = b & 1;
  const int kt0 = kh * 64 + w * 16;
  half8 Af[16], Bf[16];
#pragma unroll
  for (int t = 0; t < 16; ++t) {
    const size_t kt = kt0 + t;
    Af[t] = ldfrag(Ef + ((kt * NIT + it) * 64 + lane) * 8);
    Bf[t] = ldfrag(Vc + (kt * 64 + lane) * 8);
  }
  f32x4 acc = (f32x4){0.f, 0.f, 0.f, 0.f};
#pragma unroll
  for (int t = 0; t < 16; ++t)
    acc = __builtin_amdgcn_mfma_f32_16x16x32_f16(Af[t], Bf[t], acc, 0, 0, 0);
  float4 v; v.x = acc[0]; v.y = acc[1]; v.z = acc[2]; v.w = acc[3];
  *(float4*)&red[w * 256 + lane * 4] = v;
  __syncthreads();
  const int l = tid & 63, e = tid >> 6;
  float s = 0.f;
#pragma unroll
  for (int ww = 0; ww < 4; ++ww) s += red[ww * 256 + l * 4 + e];
  const int col = l & 15, row = (l >> 4) * 4 + e;  // C-frag mapping
  if (col == 0) P3[b * 32 + row] = s;
  else if (col == 1) P3[b * 32 + 16 + row] = s;
}

// ---- cooperative mega-kernel with LEAN custom grid barrier ------------------
__global__ __launch_bounds__(256, 2) void kAll(
    const float* __restrict__ trans, const float* __restrict__ x,
    const float* __restrict__ comms, const int* __restrict__ mask,
    const float* __restrict__ W_enc, const float* __restrict__ b_enc,
    const float* __restrict__ W_ad, const float* __restrict__ w_att,
    const float* __restrict__ W_av, const float* __restrict__ b_av,
    const float* __restrict__ W_dec, const float* __restrict__ b_dec,
    float* __restrict__ out, unsigned short* __restrict__ Ef,
    unsigned short* __restrict__ Vf, unsigned short* __restrict__ Vc,
    float* __restrict__ P, float* __restrict__ P3, unsigned* bar) {
  __shared__ __align__(16) char smem[SMEM_ALL];
  const int b = blockIdx.x, tid = threadIdx.x;
  // phase 0: 4 exp panels + 1 VS0 unit per block
#pragma unroll 1
  for (int pp = 0; pp < 4; ++pp) exp_body(b * 4 + pp, tid, trans, Ef, smem);
  __syncthreads();
  vs0_body(b, tid, x, comms, W_enc, b_enc, W_ad, w_att, W_av, b_av, Vf, smem);
  gbar(bar, tid);
  gemm_body(b, tid, Ef, Vf, P, smem);               // round 1 GEMM
  gbar(bar, tid);
  vsr_body(b, tid, P, W_ad + DQ * DQ, w_att + 2 * DQ,
           W_av + (size_t)DQ * DQ, b_av + DQ, Vf, smem);
  gbar(bar, tid);
  gemm_body(b, tid, Ef, Vf, P, smem);               // round 2 GEMM
  gbar(bar, tid);
  vsrc_body(b, tid, P, W_ad + (size_t)2 * DQ * DQ, w_att + 4 * DQ,
            W_av + (size_t)2 * DQ * DQ, b_av + 2 * DQ, W_dec, Vc, smem);
  gbar(bar, tid);
  gemmo_body(b, tid, Ef, Vc, P3, smem);             // round 3 partials
  gbar(bar, tid);
  if (b < 16) {                                     // final out
    const int i = b * 256 + tid;
    const int it = i >> 4, row = i & 15;
    const float num = P3[it * 64 + row] + P3[it * 64 + 32 + row];
    const float den = P3[it * 64 + 16 + row] + P3[it * 64 + 48 + row];
    out[i] = (mask[i] == 0) ? -INFINITY : num / den + b_dec[0];
  }
}

// ================= fallback: verified round-4 six-dispatch path ==============
__global__ __launch_bounds__(256) void kPre(
    const float* __restrict__ trans, unsigned short* __restrict__ Ef,
    const float* __restrict__ x, const float* __restrict__ comms,
    const float* __restrict__ W_enc, const float* __restrict__ b_enc,
    const float* __restrict__ W_ad_k, const float* __restrict__ wa,
    const float* __restrict__ W_av_k, const float* __restrict__ b_av_k,
    unsigned short* __restrict__ Vf) {
  __shared__ __align__(16) char smem[4 * 32 * TS * 2];
  if (blockIdx.x >= 512)
    exp_body(blockIdx.x - 512, threadIdx.x, trans, Ef, smem);
  else
    vs0_body(blockIdx.x, threadIdx.x, x, comms, W_enc, b_enc, W_ad_k, wa,
             W_av_k, b_av_k, Vf, smem);
}

__global__ __launch_bounds__(256) void kVSR(const float* __restrict__ P,
    const float* __restrict__ W_ad_k, const float* __restrict__ wa,
    const float* __restrict__ W_av_k, const float* __restrict__ b_av_k,
    unsigned short* __restrict__ Vf) {
  __shared__ __align__(16) char smem[7168];
  vsr_body(blockIdx.x, threadIdx.x, P, W_ad_k, wa, W_av_k, b_av_k, Vf, smem);
}

__global__ __launch_bounds__(256) void kVSRc(const float* __restrict__ P,
    const float* __restrict__ W_ad_k, const float* __restrict__ wa,
    const float* __restrict__ W_av_k, const float* __restrict__ b_av_k,
    const float* __restrict__ W_dec, unsigned short* __restrict__ Vc) {
  __shared__ __align__(16) char smem[7168];
  vsrc_body(blockIdx.x, threadIdx.x, P, W_ad_k, wa, W_av_k, b_av_k, W_dec, Vc, smem);
}

__global__ __launch_bounds__(256, 2) void kGemmR9(
    const unsigned short* __restrict__ Ef, const unsigned short* __restrict__ Vf,
    float* __restrict__ P) {
  __shared__ __align__(16) char smem[SMEM_ALL];
  gemm_body(blockIdx.y * 128 + blockIdx.x, threadIdx.x, Ef, Vf, P, smem);
}

__global__ __launch_bounds__(512, 2) void kGemmO(
    const unsigned short* __restrict__ Ef, const unsigned short* __restrict__ Vc,
    const float* __restrict__ b_dec, const int* __restrict__ mask,
    float* __restrict__ out) {
  __shared__ float red[8 * 256];
  __shared__ float nums[16], dens[16];
  const int tid = threadIdx.x;
  const int w = tid >> 6, lane = tid & 63;
  const int it = blockIdx.x;
  const int kt0 = w * 16;
  half8 Af[16], Bf[16];
#pragma unroll
  for (int t = 0; t < 16; ++t) {
    const size_t kt = kt0 + t;
    Af[t] = ldfrag(Ef + ((kt * NIT + it) * 64 + lane) * 8);
    Bf[t] = ldfrag(Vc + (kt * 64 + lane) * 8);
  }
  f32x4 acc = (f32x4){0.f, 0.f, 0.f, 0.f};
#pragma unroll
  for (int t = 0; t < 16; ++t)
    acc = __builtin_amdgcn_mfma_f32_16x16x32_f16(Af[t], Bf[t], acc, 0, 0, 0);
  float4 v; v.x = acc[0]; v.y = acc[1]; v.z = acc[2]; v.w = acc[3];
  *(float4*)&red[w * 256 + lane * 4] = v;
  __syncthreads();
  if (tid < 256) {
    const int l = tid & 63, e = tid >> 6;
    float s = 0.f;
#pragma unroll
    for (int ww = 0; ww < 8; ++ww) s += red[ww * 256 + l * 4 + e];
    const int col = l & 15, row = (l >> 4) * 4 + e;
    if (col == 0) nums[row] = s;
    else if (col == 1) dens[row] = s;
  }
  __syncthreads();
  if (tid < 16) {
    const int i = it * 16 + tid;
    out[i] = (mask[i] == 0) ? -INFINITY : nums[tid] / dens[tid] + b_dec[0];
  }
}

extern "C" void kernel_launch(void* const* d_in, const int* in_sizes, int n_in,
                              void* d_out, int out_size, void* d_ws, size_t ws_size,
                              hipStream_t stream) {
  (void)in_sizes; (void)n_in; (void)out_size; (void)ws_size;
  const float* trans = (const float*)d_in[2];
  const float* x     = (const float*)d_in[0];
  const float* comms = (const float*)d_in[1];
  const int*   mask  = (const int*)d_in[3];
  const float* W_enc = (const float*)d_in[4];
  const float* b_enc = (const float*)d_in[5];
  const float* W_ad  = (const float*)d_in[6];
  // d_in[7]=b_ad, d_in[9]=b_att cancel inside the row softmax
  const float* w_att = (const float*)d_in[8];
  const float* W_av  = (const float*)d_in[10];
  const float* b_av  = (const float*)d_in[11];
  const float* W_dec = (const float*)d_in[12];
  const float* b_dec = (const float*)d_in[13];
  float* out         = (float*)d_out;

  char* ws = (char*)d_ws;
  unsigned short* Vf = (unsigned short*)ws;  ws += (size_t)(N / 32) * NT * 512 * 2;
  unsigned short* Vc = (unsigned short*)ws;  ws += (size_t)(N / 32) * 512 * 2;
  unsigned short* Ef = (unsigned short*)ws;  ws += (size_t)N * N * 2;
  float* P  = (float*)ws;                    ws += (size_t)KB * N * PST9 * 4;
  float* P3 = (float*)ws;                    ws += (size_t)512 * 32 * 4;
  unsigned* bar = (unsigned*)ws;

  // zero barrier state (workspace is re-poisoned each iteration)
  hipMemsetAsync(bar, 0, 256, stream);

  void* args[] = {(void*)&trans, (void*)&x, (void*)&comms, (void*)&mask,
                  (void*)&W_enc, (void*)&b_enc, (void*)&W_ad, (void*)&w_att,
                  (void*)&W_av, (void*)&b_av, (void*)&W_dec, (void*)&b_dec,
                  (void*)&out, (void*)&Ef, (void*)&Vf, (void*)&Vc,
                  (void*)&P, (void*)&P3, (void*)&bar};
  if (hipLaunchCooperativeKernel(kAll, dim3(NBLK), dim3(256), args, 0, stream)
      == hipSuccess)
    return;

  // fallback: verified 6-dispatch path (round 4, 211 us)
  kPre<<<2560, 256, 0, stream>>>(trans, Ef, x, comms, W_enc, b_enc, W_ad,
                                 w_att, W_av, b_av, Vf);
  kGemmR9<<<dim3(128, KB), 256, 0, stream>>>(Ef, Vf, P);
  kVSR<<<N / 8, 256, 0, stream>>>(P, W_ad + (size_t)DQ * DQ,
                                  w_att + 2 * DQ, W_av + (size_t)DQ * DQ,
                                  b_av + DQ, Vf);
  kGemmR9<<<dim3(128, KB), 256, 0, stream>>>(Ef, Vf, P);
  kVSRc<<<N / 8, 256, 0, stream>>>(P, W_ad + (size_t)2 * DQ * DQ,
                                   w_att + 4 * DQ, W_av + (size_t)2 * DQ * DQ,
                                   b_av + 2 * DQ, W_dec, Vc);
  kGemmO<<<NIT, 512, 0, stream>>>(Ef, Vc, b_dec, mask, out);
}

// Round 18
// 211.978 us; speedup vs baseline: 5.1302x; 4.1142x over previous
//
#include <hip/hip_runtime.h>
#include <math.h>

#define N 4096
#define DQ 128
#define DIN 64
#define DC 32
#define NT 9          // full B panel: 9 n-tiles (128 v cols + z tile)
#define PST9 144
#define NIT 256       // N/16 i-tiles
#define KB 8          // k-splits (rounds 1-2): grid 128x8=1024 blocks = 4/CU
#define SW 4          // k-steps per wave: N / KB / 32 rows / 4 waves
#define TS 68         // exp wave-tile row stride in f16 units
#define SMEM_ALL 36864

typedef __attribute__((ext_vector_type(8))) short short8;
typedef __attribute__((ext_vector_type(8))) _Float16 half8;
typedef __attribute__((ext_vector_type(4))) float f32x4;
typedef __attribute__((ext_vector_type(4))) unsigned short us4;

__device__ __forceinline__ unsigned short f2h(float x) {
  return __builtin_bit_cast(unsigned short, (_Float16)x);
}
__device__ __forceinline__ half8 ldfrag(const unsigned short* p) {
  return __builtin_bit_cast(half8, *(const short8*)p);
}

// u = W_ad_k . wa (float4 row reads)
__device__ __forceinline__ void u_calc(int tid, const float* __restrict__ W_ad_k,
                                       const float* __restrict__ wa, float* u) {
  if (tid < DQ) {
    float s = 0.f;
    const float* wrow = &W_ad_k[tid * DQ];
    for (int q = 0; q < DQ; q += 4) {
      const float4 wv = *(const float4*)&wrow[q];
      const float4 av = *(const float4*)&wa[q];
      s += wv.x * av.x + wv.y * av.y + wv.z * av.z + wv.w * av.w;
    }
    u[tid] = s;
  }
}

// p*(h@W_av+b_av) -> single f16 tile in LDS
__device__ __forceinline__ void v_phase(const float* hs_row, float p,
    const float* __restrict__ W_av_k, const float* __restrict__ b_av_k,
    int r, int d4, unsigned short* shh) {
  float a[4] = {b_av_k[d4], b_av_k[d4 + 1], b_av_k[d4 + 2], b_av_k[d4 + 3]};
  for (int c = 0; c < DQ; ++c) {
    const float hv = hs_row[c];
    const float4 w = *(const float4*)&W_av_k[c * DQ + d4];
    a[0] += hv * w.x; a[1] += hv * w.y; a[2] += hv * w.z; a[3] += hv * w.w;
  }
  const int nt = d4 >> 4;
#pragma unroll
  for (int e = 0; e < 4; ++e)
    shh[nt * 128 + ((d4 + e) & 15) * 8 + r] = f2h(p * a[e]);
  const int c32 = d4 >> 2;
  if (c32 < 16)
    shh[8 * 128 + c32 * 8 + r] = (c32 == 0) ? f2h(p) : 0;
}

__device__ __forceinline__ void v_store(int tid, int blk,
    const unsigned short* shh, unsigned short* __restrict__ Vf) {
  const int kt = blk >> 2, quad = blk & 3;
  if (tid < NT * 16) {
    const int nt = tid >> 4, l15 = tid & 15;
    const size_t dst = (((size_t)kt * NT + nt) * 64 + quad * 16 + l15) * 8;
    *(short8*)(Vf + dst) = *(const short8*)&shh[nt * 128 + l15 * 8];
  }
}

// ---- one 32x256 exp panel: wave-private, barrier-free ----------------------
__device__ __forceinline__ void exp_body(int pid, int tid,
    const float* __restrict__ trans, unsigned short* __restrict__ Ef,
    char* smem) {
  const int ip = pid & 15;          // i-panel of 256
  const int kt = pid >> 4;          // k-tile of 32
  const int w = tid >> 6, lane = tid & 63;
  const int quad = lane >> 4, l15 = lane & 15;
  unsigned short* lt = (unsigned short*)smem + w * (32 * TS);
  float4 v[8];
#pragma unroll
  for (int p = 0; p < 8; ++p) {
    const int r = 4 * p + quad;
    v[p] = *(const float4*)&trans[(size_t)(kt * 32 + r) * N + ip * 256 + w * 64 + 4 * l15];
  }
#pragma unroll
  for (int p = 0; p < 8; ++p) {
    const int r = 4 * p + quad;
    us4 pv;
    pv.x = f2h(__expf(v[p].x)); pv.y = f2h(__expf(v[p].y));
    pv.z = f2h(__expf(v[p].z)); pv.w = f2h(__expf(v[p].w));
    *(us4*)&lt[r * TS + 4 * l15] = pv;
  }
  asm volatile("s_waitcnt lgkmcnt(0)" ::: "memory");  // in-wave write->read fence
#pragma unroll
  for (int s = 0; s < 4; ++s) {
    unsigned short hb[8];
#pragma unroll
    for (int jj = 0; jj < 8; ++jj)
      hb[jj] = lt[(quad * 8 + jj) * TS + s * 16 + l15];
    const short8 sv = {(short)hb[0], (short)hb[1], (short)hb[2], (short)hb[3],
                       (short)hb[4], (short)hb[5], (short)hb[6], (short)hb[7]};
    const int itt = ip * 16 + 4 * w + s;
    *(short8*)(Ef + (((size_t)kt * NIT + itt) * 64 + lane) * 8) = sv;
  }
}

// ---- round 0: encode + sa + p + V' (8 rows per unit) ------------------------
__device__ __forceinline__ void vs0_body(int blk, int tid,
    const float* __restrict__ x, const float* __restrict__ comms,
    const float* __restrict__ W_enc, const float* __restrict__ b_enc,
    const float* __restrict__ W_ad0, const float* __restrict__ wa0,
    const float* __restrict__ W_av0, const float* __restrict__ b_av0,
    unsigned short* __restrict__ Vf, char* smem) {
  float(*xs)[96] = (float(*)[96])smem;                       // 3072 B
  float(*hs)[DQ] = (float(*)[DQ])(smem + 3072);              // 4096 B
  float* u = (float*)(smem + 7168);                          // 512 B
  float* pb = (float*)(smem + 7680);                         // 32 B
  unsigned short* shh = (unsigned short*)(smem + 7712);      // 2304 B
  if (tid < 128) {
    const float4 vv = *(const float4*)&x[(size_t)blk * 8 * DIN + tid * 4];
    const int idx = tid * 4, r = idx >> 6, c = idx & 63;
    xs[r][c] = vv.x; xs[r][c + 1] = vv.y; xs[r][c + 2] = vv.z; xs[r][c + 3] = vv.w;
  } else if (tid < 192) {
    const int t = tid - 128;
    const float4 vv = *(const float4*)&comms[(size_t)blk * 8 * DC + t * 4];
    const int idx = t * 4, r = idx >> 5, c = idx & 31;
    xs[r][64 + c] = vv.x; xs[r][64 + c + 1] = vv.y;
    xs[r][64 + c + 2] = vv.z; xs[r][64 + c + 3] = vv.w;
  }
  u_calc(tid, W_ad0, wa0, u);
  __syncthreads();
  const int r = tid >> 5, c32 = tid & 31, d4 = c32 * 4;
  {
    float a0 = b_enc[d4], a1 = b_enc[d4 + 1], a2 = b_enc[d4 + 2], a3 = b_enc[d4 + 3];
    for (int c = 0; c < 96; ++c) {
      const float hv = xs[r][c];
      const float4 w = *(const float4*)&W_enc[c * DQ + d4];
      a0 += hv * w.x; a1 += hv * w.y; a2 += hv * w.z; a3 += hv * w.w;
    }
    hs[r][d4] = a0; hs[r][d4 + 1] = a1; hs[r][d4 + 2] = a2; hs[r][d4 + 3] = a3;
  }
  __syncthreads();
  float part = 0.f;
  for (int c = c32; c < DQ; c += 32) part += hs[r][c] * u[c];
#pragma unroll
  for (int m = 16; m > 0; m >>= 1) part += __shfl_xor(part, m, 32);
  if (c32 == 0) pb[r] = __expf(part);
  __syncthreads();
  v_phase(hs[r], pb[r], W_av0, b_av0, r, d4, shh);
  __syncthreads();
  v_store(tid, blk, shh, Vf);
}

// ---- fused kVS0 + kExp: VS0 blocks FIRST (overlap, no tail) -----------------
__global__ __launch_bounds__(256) void kPre(
    const float* __restrict__ trans, unsigned short* __restrict__ Ef,
    const float* __restrict__ x, const float* __restrict__ comms,
    const float* __restrict__ W_enc, const float* __restrict__ b_enc,
    const float* __restrict__ W_ad_k, const float* __restrict__ wa,
    const float* __restrict__ W_av_k, const float* __restrict__ b_av_k,
    unsigned short* __restrict__ Vf) {
  __shared__ __align__(16) char smem[4 * 32 * TS * 2];
  if (blockIdx.x >= 512)
    exp_body(blockIdx.x - 512, threadIdx.x, trans, Ef, smem);
  else
    vs0_body(blockIdx.x, threadIdx.x, x, comms, W_enc, b_enc, W_ad_k, wa,
             W_av_k, b_av_k, Vf, smem);
}

// ---- round 1: P-reduce (KB slices) -> h + sa + p + V' -----------------------
__global__ __launch_bounds__(256) void kVSR(const float* __restrict__ P,
    const float* __restrict__ W_ad_k, const float* __restrict__ wa,
    const float* __restrict__ W_av_k, const float* __restrict__ b_av_k,
    unsigned short* __restrict__ Vf) {
  __shared__ float hs[8][DQ];
  __shared__ float u[DQ];
  __shared__ float pb[8];
  __shared__ __align__(16) unsigned short shh[NT * 128];
  const int tid = threadIdx.x;
  const int r = tid >> 5, c32 = tid & 31, d4 = c32 * 4;
  const int j = blockIdx.x * 8 + r;
  u_calc(tid, W_ad_k, wa, u);
  float4 num = {0.f, 0.f, 0.f, 0.f};
  float den = 0.f;
#pragma unroll
  for (int s = 0; s < KB; ++s) {
    const float* b = &P[((size_t)s * N + j) * PST9];
    const float4 v = *(const float4*)&b[d4];
    num.x += v.x; num.y += v.y; num.z += v.z; num.w += v.w;
    den += b[128];
  }
  const float inv = 1.f / den;
  hs[r][d4] = num.x * inv; hs[r][d4 + 1] = num.y * inv;
  hs[r][d4 + 2] = num.z * inv; hs[r][d4 + 3] = num.w * inv;
  __syncthreads();
  float part = 0.f;
  for (int c = c32; c < DQ; c += 32) part += hs[r][c] * u[c];
#pragma unroll
  for (int m = 16; m > 0; m >>= 1) part += __shfl_xor(part, m, 32);
  if (c32 == 0) pb[r] = __expf(part);
  __syncthreads();
  v_phase(hs[r], pb[r], W_av_k, b_av_k, r, d4, shh);
  __syncthreads();
  v_store(tid, blockIdx.x, shh, Vf);
}

// ---- round 2: P-reduce -> h + sa + p + CONTRACTED V' ------------------------
__global__ __launch_bounds__(256) void kVSRc(const float* __restrict__ P,
    const float* __restrict__ W_ad_k, const float* __restrict__ wa,
    const float* __restrict__ W_av_k, const float* __restrict__ b_av_k,
    const float* __restrict__ W_dec, unsigned short* __restrict__ Vc) {
  __shared__ float hs[8][DQ];
  __shared__ float u[DQ];
  __shared__ float pb[8];
  const int tid = threadIdx.x;
  const int r = tid >> 5, c32 = tid & 31, d4 = c32 * 4;
  const int j = blockIdx.x * 8 + r;
  u_calc(tid, W_ad_k, wa, u);
  float4 num = {0.f, 0.f, 0.f, 0.f};
  float den = 0.f;
#pragma unroll
  for (int s = 0; s < KB; ++s) {
    const float* b = &P[((size_t)s * N + j) * PST9];
    const float4 v = *(const float4*)&b[d4];
    num.x += v.x; num.y += v.y; num.z += v.z; num.w += v.w;
    den += b[128];
  }
  const float inv = 1.f / den;
  hs[r][d4] = num.x * inv; hs[r][d4 + 1] = num.y * inv;
  hs[r][d4 + 2] = num.z * inv; hs[r][d4 + 3] = num.w * inv;
  __syncthreads();
  float part = 0.f;
  for (int c = c32; c < DQ; c += 32) part += hs[r][c] * u[c];
#pragma unroll
  for (int m = 16; m > 0; m >>= 1) part += __shfl_xor(part, m, 32);
  if (c32 == 0) pb[r] = __expf(part);
  __syncthreads();
  float a[4] = {b_av_k[d4], b_av_k[d4 + 1], b_av_k[d4 + 2], b_av_k[d4 + 3]};
  for (int c = 0; c < DQ; ++c) {
    const float hv = hs[r][c];
    const float4 w = *(const float4*)&W_av_k[c * DQ + d4];
    a[0] += hv * w.x; a[1] += hv * w.y; a[2] += hv * w.z; a[3] += hv * w.w;
  }
  float vd = a[0] * W_dec[d4] + a[1] * W_dec[d4 + 1]
           + a[2] * W_dec[d4 + 2] + a[3] * W_dec[d4 + 3];
#pragma unroll
  for (int m = 16; m > 0; m >>= 1) vd += __shfl_xor(vd, m, 32);
  const float p = pb[r];
  if (c32 < 16) {
    const int blk = blockIdx.x;
    const size_t ix = (((size_t)(blk >> 2)) * 64 + (blk & 3) * 16 + c32) * 8 + r;
    Vc[ix] = (c32 == 0) ? f2h(p * vd) : (c32 == 1) ? f2h(p) : 0;
  }
}

// ---- MFMA GEMM: B direct-to-VGPR dbuf, 36 KB two-pass epilogue --------------
// KB=8 -> grid 128x8 = 1024 blocks = 4 blocks/CU (LDS 36.9KB, VGPR ~128):
// doubles wave residency vs KB=4's 2/CU without changing per-block A/B traffic.
__global__ __launch_bounds__(256, 2) void kGemmR9(
    const unsigned short* __restrict__ Ef, const unsigned short* __restrict__ Vf,
    float* __restrict__ P) {
  __shared__ __align__(16) float lf[4 * NT * 256];   // 36864 B
  const int tid = threadIdx.x;
  const int w = tid >> 6, lane = tid & 63;
  const int quad = lane >> 4, l15 = lane & 15;
  const int it0 = blockIdx.x * 2;
  const int y = blockIdx.y;
  const size_t ktw = (size_t)y * (4 * SW) + w * SW;

  f32x4 acc[2][NT];
#pragma unroll
  for (int ti = 0; ti < 2; ++ti)
#pragma unroll
    for (int nt = 0; nt < NT; ++nt) acc[ti][nt] = (f32x4){0.f, 0.f, 0.f, 0.f};

  const unsigned short* Ap = Ef + (ktw * NIT + it0) * 512 + lane * 8;
  const unsigned short* Bp = Vf + ktw * (NT * 512) + lane * 8;

  half8 A0[2], A1[2], B0[NT], B1[NT];
#pragma unroll
  for (int ti = 0; ti < 2; ++ti) A0[ti] = ldfrag(Ap + ti * 512);
#pragma unroll
  for (int nt = 0; nt < NT; ++nt) B0[nt] = ldfrag(Bp + nt * 512);

#pragma unroll
  for (int t = 0; t < SW; ++t) {
    if (t + 1 < SW) {
      const unsigned short* An = Ap + (size_t)(t + 1) * (NIT * 512);
      const unsigned short* Bn = Bp + (size_t)(t + 1) * (NT * 512);
#pragma unroll
      for (int nt = 0; nt < NT; ++nt) B1[nt] = ldfrag(Bn + nt * 512);
#pragma unroll
      for (int ti = 0; ti < 2; ++ti) A1[ti] = ldfrag(An + ti * 512);
    }
#pragma unroll
    for (int nt = 0; nt < NT; ++nt) {
      acc[0][nt] = __builtin_amdgcn_mfma_f32_16x16x32_f16(A0[0], B0[nt], acc[0][nt], 0, 0, 0);
      acc[1][nt] = __builtin_amdgcn_mfma_f32_16x16x32_f16(A0[1], B0[nt], acc[1][nt], 0, 0, 0);
    }
    if (t + 1 < SW) {
      A0[0] = A1[0]; A0[1] = A1[1];
#pragma unroll
      for (int nt = 0; nt < NT; ++nt) B0[nt] = B1[nt];
    }
  }
  float* Pb = P + (size_t)y * N * PST9;
#pragma unroll
  for (int ti = 0; ti < 2; ++ti) {
    __syncthreads();
#pragma unroll
    for (int nt = 0; nt < NT; ++nt) {
      float4 v; v.x = acc[ti][nt][0]; v.y = acc[ti][nt][1];
      v.z = acc[ti][nt][2]; v.w = acc[ti][nt][3];
      *(float4*)&lf[(w * NT + nt) * 256 + lane * 4] = v;
    }
    __syncthreads();
    for (int p = w; p < NT; p += 4) {
      float4 s = {0.f, 0.f, 0.f, 0.f};
#pragma unroll
      for (int wv = 0; wv < 4; ++wv) {
        const float4 v = *(const float4*)&lf[(wv * NT + p) * 256 + lane * 4];
        s.x += v.x; s.y += v.y; s.z += v.z; s.w += v.w;
      }
      const float sr[4] = {s.x, s.y, s.z, s.w};
      if (p != 8 || l15 == 0) {
#pragma unroll
        for (int r2 = 0; r2 < 4; ++r2) {
          const int i = (it0 + ti) * 16 + quad * 4 + r2;
          Pb[(size_t)i * PST9 + p * 16 + l15] = sr[r2];
        }
      }
    }
  }
}

// ---- round 3 GEMM + out fused: 1 i-tile/block, 8 waves split full k --------
__global__ __launch_bounds__(512, 2) void kGemmO(
    const unsigned short* __restrict__ Ef, const unsigned short* __restrict__ Vc,
    const float* __restrict__ b_dec, const int* __restrict__ mask,
    float* __restrict__ out) {
  __shared__ float red[8 * 256];
  __shared__ float nums[16], dens[16];
  const int tid = threadIdx.x;
  const int w = tid >> 6, lane = tid & 63;
  const int it = blockIdx.x;
  const int kt0 = w * 16;
  half8 Af[16], Bf[16];
#pragma unroll
  for (int t = 0; t < 16; ++t) {
    const size_t kt = kt0 + t;
    Af[t] = ldfrag(Ef + ((kt * NIT + it) * 64 + lane) * 8);
    Bf[t] = ldfrag(Vc + (kt * 64 + lane) * 8);
  }
  f32x4 acc = (f32x4){0.f, 0.f, 0.f, 0.f};
#pragma unroll
  for (int t = 0; t < 16; ++t)
    acc = __builtin_amdgcn_mfma_f32_16x16x32_f16(Af[t], Bf[t], acc, 0, 0, 0);
  float4 v; v.x = acc[0]; v.y = acc[1]; v.z = acc[2]; v.w = acc[3];
  *(float4*)&red[w * 256 + lane * 4] = v;
  __syncthreads();
  if (tid < 256) {
    const int l = tid & 63, e = tid >> 6;
    float s = 0.f;
#pragma unroll
    for (int ww = 0; ww < 8; ++ww) s += red[ww * 256 + l * 4 + e];
    const int col = l & 15, row = (l >> 4) * 4 + e;
    if (col == 0) nums[row] = s;
    else if (col == 1) dens[row] = s;
  }
  __syncthreads();
  if (tid < 16) {
    const int i = it * 16 + tid;
    out[i] = (mask[i] == 0) ? -INFINITY : nums[tid] / dens[tid] + b_dec[0];
  }
}

extern "C" void kernel_launch(void* const* d_in, const int* in_sizes, int n_in,
                              void* d_out, int out_size, void* d_ws, size_t ws_size,
                              hipStream_t stream) {
  (void)in_sizes; (void)n_in; (void)out_size; (void)ws_size;
  const float* x     = (const float*)d_in[0];
  const float* comms = (const float*)d_in[1];
  const float* trans = (const float*)d_in[2];
  const int*   mask  = (const int*)d_in[3];
  const float* W_enc = (const float*)d_in[4];
  const float* b_enc = (const float*)d_in[5];
  const float* W_ad  = (const float*)d_in[6];
  // d_in[7]=b_ad, d_in[9]=b_att cancel inside the row softmax
  const float* w_att = (const float*)d_in[8];
  const float* W_av  = (const float*)d_in[10];
  const float* b_av  = (const float*)d_in[11];
  const float* W_dec = (const float*)d_in[12];
  const float* b_dec = (const float*)d_in[13];
  float* out         = (float*)d_out;

  char* ws = (char*)d_ws;
  unsigned short* Vf = (unsigned short*)ws;  ws += (size_t)(N / 32) * NT * 512 * 2;
  unsigned short* Vc = (unsigned short*)ws;  ws += (size_t)(N / 32) * 512 * 2;
  unsigned short* Ef = (unsigned short*)ws;  ws += (size_t)N * N * 2;
  float* P  = (float*)ws;

  kPre<<<2560, 256, 0, stream>>>(trans, Ef, x, comms, W_enc, b_enc, W_ad,
                                 w_att, W_av, b_av, Vf);
  kGemmR9<<<dim3(128, KB), 256, 0, stream>>>(Ef, Vf, P);
  kVSR<<<N / 8, 256, 0, stream>>>(P, W_ad + (size_t)DQ * DQ,
                                  w_att + 2 * DQ, W_av + (size_t)DQ * DQ,
                                  b_av + DQ, Vf);
  kGemmR9<<<dim3(128, KB), 256, 0, stream>>>(Ef, Vf, P);
  kVSRc<<<N / 8, 256, 0, stream>>>(P, W_ad + (size_t)2 * DQ * DQ,
                                   w_att + 4 * DQ, W_av + (size_t)2 * DQ * DQ,
                                   b_av + 2 * DQ, W_dec, Vc);
  kGemmO<<<NIT, 512, 0, stream>>>(Ef, Vc, b_dec, mask, out);
}